// Round 7
// baseline (7974.755 us; speedup 1.0000x reference)
//
#include <hip/hip_runtime.h>
#include <cstddef>
#include <cstdint>

// 2-layer LSTM decoder, B=2048, Z=64, H=256, D=8, T=250. fp32 in/out.
//
// R7: i8 hi/lo numerics (R6, absmax 2.2e-3 verified) with the weight stream
// moved OFF VGPRs onto per-wave 3-slot LDS rings via global_load_lds.
// R5/R6 post-mortem: allocator pins 128 arch VGPRs when MFMA is present;
// bufA/bufB (128 VGPRs) forced ~600 B/thread/step of loop-invariant spill
// reloads -> 10 GB HBM traffic + L2 thrash. LDS rings cost 0 VGPRs.
//  - Ring slots continue across phases: each phase's first 3 tiles are issued
//    in the previous phase's tail, so barrier vmcnt-drains land data early
//    instead of stalling a cold restart.
//  - Wih0 bf16 in LDS (16 KB); out-proj reads h1 hi/lo planes directly
//    (15-bit h) + __shfl_xor reduce (pout/h1f/barrier-e eliminated).
//  - LDS 62 KB; per-CU weight stream 768 KB/step.

#define BSZ    2048
#define ZDIM   64
#define HDIM   256
#define DDIM   8
#define TSTEPS 250
#define ROWS   16
#define NWG    (BSZ / ROWS)   // 128
#define NTH    512            // 8 waves
#define G4     1024
#define WSTR   264            // woutT row stride (shorts)

typedef __attribute__((ext_vector_type(4))) int v4i;

__device__ __forceinline__ unsigned short f2bf(float x) {   // RNE f32->bf16
  union { float f; unsigned u; } v; v.f = x;
  unsigned r = v.u + 0x7fff + ((v.u >> 16) & 1);
  return (unsigned short)(r >> 16);
}
__device__ __forceinline__ float bf2f(unsigned short b) {
  union { unsigned u; float f; } v; v.u = (unsigned)b << 16; return v.f;
}
__device__ __forceinline__ float fexp2(float x) { return __builtin_amdgcn_exp2f(x); }
__device__ __forceinline__ float frcp(float x)  { return __builtin_amdgcn_rcpf(x); }
__device__ __forceinline__ float sigm(float x)  { return frcp(1.f + fexp2(-1.44269504f * x)); }
__device__ __forceinline__ float tanh_(float x) { return 2.f * frcp(1.f + fexp2(-2.88539008f * x)) - 1.f; }
__device__ __forceinline__ char q8(float x, float s) {
  float v = fminf(fmaxf(x * s, -127.f), 127.f);
  return (char)(int)__builtin_rintf(v);
}
// h*s split into hi + lo/254 (lo in [-127,127] exactly since 0.5*254=127)
__device__ __forceinline__ void q8pair(float h, float s, char* hi, char* lo) {
  float hs = fminf(fmaxf(h * s, -127.f), 127.f);
  float hq = __builtin_rintf(hs);
  *hi = (char)(int)hq;
  *lo = (char)(int)__builtin_rintf((hs - hq) * 254.f);
}

// async 16B/lane global->LDS DMA (verified R3): lands at ldsbase + lane*16
__device__ __forceinline__ void async_copy16(const void* g, void* l) {
  __builtin_amdgcn_global_load_lds(
      reinterpret_cast<const __attribute__((address_space(1))) unsigned int*>(
          reinterpret_cast<uintptr_t>(g)),
      reinterpret_cast<__attribute__((address_space(3))) unsigned int*>(
          reinterpret_cast<uintptr_t>(l)),
      16, 0, 0);
}
// s_waitcnt vmcnt(N) only
template <int N>
__device__ __forceinline__ void wait_vmcnt() {
  __builtin_amdgcn_s_waitcnt((N & 15) | (7 << 4) | (15 << 8) | (((N >> 4) & 3) << 14));
}

// ---------------- initial state (mapping verified R1-R6) ----------------
__global__ void init_state(const float* __restrict__ z,
                           const float* __restrict__ Wfh, const float* __restrict__ bfh,
                           const float* __restrict__ Wfc, const float* __restrict__ bfc,
                           char* __restrict__ h0h, char* __restrict__ h0l,
                           char* __restrict__ h1h, char* __restrict__ h1l,
                           float* __restrict__ c0s, float* __restrict__ c1s)
{
  int idx = blockIdx.x * 256 + threadIdx.x;
  int b = idx >> 8;
  int j = idx & 255;
  int col = ((b & 1) << 8) | j;
  const float* z0 = z + (size_t)(b >> 1) * ZDIM;
  const float* z1 = z + (size_t)(1024 + (b >> 1)) * ZDIM;
  float h0 = bfh[col], c0v = bfc[col], h1 = bfh[col], c1v = bfc[col];
  for (int k = 0; k < ZDIM; ++k) {
    float wh = Wfh[k * 512 + col];
    float wc = Wfc[k * 512 + col];
    float a = z0[k], bb = z1[k];
    h0  += a * wh;  c0v += a * wc;
    h1  += bb * wh; c1v += bb * wc;
  }
  char hi, lo;
  q8pair(h0, 31.75f, &hi, &lo); h0h[idx] = hi; h0l[idx] = lo;
  q8pair(h1, 31.75f, &hi, &lo); h1h[idx] = hi; h1l[idx] = lo;
  c0s[idx] = c0v; c1s[idx] = c1v;
}

// ---------------- per-output-column scales (unchanged) ----------------
__global__ void col_scales(const float* __restrict__ Whh0,
                           const float* __restrict__ Wih1, const float* __restrict__ Whh1,
                           float* __restrict__ cs0, float* __restrict__ qs0,
                           float* __restrict__ cs1, float* __restrict__ qs1)
{
  int c = blockIdx.x * 256 + threadIdx.x;   // 0..2047
  if (c < 1024) {
    float m = 0.f;
    for (int k = 0; k < 256; ++k) m = fmaxf(m, fabsf(Whh0[(size_t)k * G4 + c]));
    cs0[c] = m * (1.f / 16129.f);
    qs0[c] = 127.f / m;
  } else {
    c -= 1024;
    float m = 0.f;
    for (int k = 0; k < 256; ++k) m = fmaxf(m, fabsf(Whh1[(size_t)k * G4 + c]));
    for (int k = 0; k < 256; ++k) m = fmaxf(m, fabsf(Wih1[(size_t)k * G4 + c]));
    cs1[c] = m * (1.f / 16129.f);
    qs1[c] = 127.f / m;
  }
}

// ------- i8 weight pack, order [kc][wave][tile][lane] (verified R4-R6) -----
__global__ void pack_i8(const float* __restrict__ Whh0,
                        const float* __restrict__ Wih1, const float* __restrict__ Whh1,
                        const float* __restrict__ qs0, const float* __restrict__ qs1,
                        char* __restrict__ p0, char* __restrict__ p1)
{
  int tt   = blockIdx.x * 4 + (threadIdx.x >> 6);   // 0..767
  int lane = threadIdx.x & 63;
  int l15 = lane & 15, lq = lane >> 4;
  union { char c[16]; uint4 u; } v;
  if (tt < 256) {                                   // layer0: 4 kc x 8 w x 8 i
    int kc = tt >> 6, w = (tt >> 3) & 7, i = tt & 7;
    int nt = (i >> 1) * 16 + 2 * w + (i & 1);
    int col = nt * 16 + l15;
    float q = qs0[col];
    for (int j = 0; j < 16; ++j) {
      int k = kc * 64 + lq * 16 + j;
      v.c[j] = q8(Whh0[(size_t)k * G4 + col], q);
    }
    *(uint4*)(p0 + (size_t)tt * 1024 + lane * 16) = v.u;
  } else {                                          // layer1: 8 kc x 8 w x 8 i
    int t1 = tt - 256;
    int kc = t1 >> 6, w = (t1 >> 3) & 7, i = t1 & 7;
    int nt = (i >> 1) * 16 + 2 * w + (i & 1);
    int col = nt * 16 + l15;
    float q = qs1[col];
    for (int j = 0; j < 16; ++j) {
      int k = kc * 64 + lq * 16 + j;
      float wv = (k < 256) ? Whh1[(size_t)k * G4 + col]
                           : Wih1[(size_t)(k - 256) * G4 + col];
      v.c[j] = q8(wv, q);
    }
    *(uint4*)(p1 + (size_t)t1 * 1024 + lane * 16) = v.u;
  }
}

// ---------------- persistent LSTM kernel ----------------
__global__ __launch_bounds__(NTH, 1) void lstm_run(
    const float* __restrict__ target,
    const char* __restrict__ p0, const char* __restrict__ p1,
    const float* __restrict__ bih0, const float* __restrict__ bhh0,
    const float* __restrict__ bih1, const float* __restrict__ bhh1,
    const float* __restrict__ Wih0,            // [8,1024] fp32 -> bf16 LDS
    const float* __restrict__ Wout, const float* __restrict__ bout,
    const char* __restrict__ h0h, const char* __restrict__ h0l,
    const char* __restrict__ h1h, const char* __restrict__ h1l,
    const float* __restrict__ c0s, const float* __restrict__ c1s,
    const float* __restrict__ cs0, const float* __restrict__ cs1,
    float* __restrict__ out)
{
  __shared__ uint4 ring[8][3][64];                 // 24 KB: per-wave 3x1KB slots
  __shared__ uint4 X4h[32 * 16];                   // 8 KB (blk: 0..15 h1, 16..31 h0)
  __shared__ uint4 X4l[32 * 16];                   // 8 KB
  __shared__ unsigned short wih0b[DDIM * G4];      // 16 KB bf16
  __shared__ unsigned short woutT[8 * WSTR];       // 4.1 KB bf16
  __shared__ float x_lds[16 * 8];                  // 0.5 KB  (total ~62 KB)

  const int tid  = threadIdx.x;
  const int w    = tid >> 6;
  const int lane = tid & 63;
  const int l15  = lane & 15;
  const int lq   = lane >> 4;
  const int b0   = blockIdx.x * ROWS;
  const int rot0 = blockIdx.x & 3;
  const int rot1 = blockIdx.x & 7;
  char* Xch = (char*)X4h;
  char* Xcl = (char*)X4l;

  // ---- one-time staging ----
  {
    int m = tid & 15, blk = tid >> 4;              // 32 blks x 16 m
    const char* sh = (blk < 16) ? h1h : h0h;
    const char* sl = (blk < 16) ? h1l : h0l;
    int jblk = blk & 15;
    X4h[blk * 16 + m] = *(const uint4*)(sh + (size_t)(b0 + m) * HDIM + jblk * 16);
    X4l[blk * 16 + m] = *(const uint4*)(sl + (size_t)(b0 + m) * HDIM + jblk * 16);
  }
  for (int i = tid; i < DDIM * G4; i += NTH) wih0b[i] = f2bf(Wih0[i]);
  for (int i = tid; i < HDIM * DDIM; i += NTH) {
    int k = i >> 3, d = i & 7;
    woutT[d * WSTR + k] = f2bf(Wout[i]);
  }

  const int myrow = lq * 4;
  const int jc0   = 32 * w + l15;
  float c0r[2][4], c1r[2][4];
  float bA0[8], bA1[8], csA0[8], csA1[8];          // flat [g*2+cc]
#pragma unroll
  for (int i = 0; i < 8; ++i) {
    int col = (i >> 1) * 256 + jc0 + 16 * (i & 1);
    bA0[i]  = bih0[col] + bhh0[col];
    bA1[i]  = bih1[col] + bhh1[col];
    csA0[i] = cs0[col];
    csA1[i] = cs1[col];
  }
#pragma unroll
  for (int cc = 0; cc < 2; ++cc) {
    int j = jc0 + cc * 16;
#pragma unroll
    for (int r = 0; r < 4; ++r) {
      c0r[cc][r] = c0s[(size_t)(b0 + myrow + r) * HDIM + j];
      c1r[cc][r] = c1s[(size_t)(b0 + myrow + r) * HDIM + j];
    }
  }
  const int opr = tid >> 5, opd = (tid >> 2) & 7, opq = tid & 3;
  const float bo_out = bout[opd];

  // per-lane weight stream bases (byte ptrs); tile (kc,i): + (kc<<16) + (i<<10)
  const char* gp0 = p0 + (size_t)w * 8192 + lane * 16;
  const char* gp1 = p1 + (size_t)w * 8192 + lane * 16;

#define A0VH(KC) __builtin_bit_cast(v4i, X4h[(16 + (KC) * 4 + lq) * 16 + l15])
#define A0VL(KC) __builtin_bit_cast(v4i, X4l[(16 + (KC) * 4 + lq) * 16 + l15])
#define A1VH(KC) __builtin_bit_cast(v4i, X4h[((KC) * 4 + lq) * 16 + l15])
#define A1VL(KC) __builtin_bit_cast(v4i, X4l[((KC) * 4 + lq) * 16 + l15])

  // initial prologue: L0 tiles 0,1,2 (kc group rot0) into slots 0,1,2
  async_copy16(gp0 + ((size_t)rot0 << 16),          &ring[w][0][0]);
  async_copy16(gp0 + ((size_t)rot0 << 16) + 1024,   &ring[w][1][0]);
  async_copy16(gp0 + ((size_t)rot0 << 16) + 2048,   &ring[w][2][0]);

  __syncthreads();

#pragma unroll 1
  for (int t = 0; t < TSTEPS; ++t) {
    // ---- teacher-forced input (fp32) ----
    if (tid < 128) {
      int m = tid >> 3, d = tid & 7;
      x_lds[m * 8 + d] = (t == 0) ? 0.f
          : target[(size_t)(b0 + m) * (TSTEPS * DDIM) + (size_t)(t - 1) * DDIM + d];
    }
    __syncthreads();   // (1) x visible; vmcnt drained -> ring slots 0..2 landed

    const float sc0 = (t <= 1) ? 4.f : 1.f;
    const float sc1 = (t == 0) ? 4.f : 1.f;
    const float wq0 = (t == 0) ? 31.75f : 127.f;

    v4i acch[8], accl[8];
    const v4i zi = {0, 0, 0, 0};

    // ================= layer 0: h0 @ Whh0 (32 tiles, slot = j%3) ============
#pragma unroll
    for (int i = 0; i < 8; ++i) { acch[i] = zi; accl[i] = zi; }
    {
      v4i ah, al;
#pragma unroll
      for (int j = 0; j < 32; ++j) {
        const int i = j & 7, s = j % 3;
        if (i == 0) { int kcr = ((j >> 3) + rot0) & 3; ah = A0VH(kcr); al = A0VL(kcr); }
        wait_vmcnt<2>();
        v4i bb = __builtin_bit_cast(v4i, ring[w][s][lane]);
        acch[i] = __builtin_amdgcn_mfma_i32_16x16x64_i8(ah, bb, acch[i], 0, 0, 0);
        accl[i] = __builtin_amdgcn_mfma_i32_16x16x64_i8(al, bb, accl[i], 0, 0, 0);
        const int jn = j + 3;
        if (jn < 32) {
          int kcr = ((jn >> 3) + rot0) & 3;
          async_copy16(gp0 + ((size_t)kcr << 16) + ((size_t)(jn & 7) << 10), &ring[w][s][0]);
        } else {           // L1 prologue tiles 0..2 -> slots (j1+2)%3
          int j1 = jn - 32;
          async_copy16(gp1 + ((size_t)rot1 << 16) + ((size_t)j1 << 10), &ring[w][s][0]);
        }
      }
    }
    __syncthreads();   // (a) L0 A-reads done; L1 prologue drained (landed)

    // ---- cell 0: dequant + fp32 x-path (bf16 weights) + activations ----
    {
      float xv[4][8];
#pragma unroll
      for (int r = 0; r < 4; ++r) {
        float4 plo = *(const float4*)&x_lds[(myrow + r) * 8];
        float4 phi = *(const float4*)&x_lds[(myrow + r) * 8 + 4];
        xv[r][0] = plo.x; xv[r][1] = plo.y; xv[r][2] = plo.z; xv[r][3] = plo.w;
        xv[r][4] = phi.x; xv[r][5] = phi.y; xv[r][6] = phi.z; xv[r][7] = phi.w;
      }
#pragma unroll
      for (int cc = 0; cc < 2; ++cc) {
        float gf4[4][4];
#pragma unroll
        for (int g = 0; g < 4; ++g) {
          int i = g * 2 + cc;
          float cs = csA0[i] * sc0;
#pragma unroll
          for (int r = 0; r < 4; ++r)
            gf4[g][r] = ((float)acch[i][r] + (float)accl[i][r] * (1.f / 254.f)) * cs + bA0[i];
        }
#pragma unroll
        for (int d = 0; d < 8; ++d) {
          float w4[4];
#pragma unroll
          for (int g = 0; g < 4; ++g)
            w4[g] = bf2f(wih0b[d * G4 + g * 256 + jc0 + 16 * cc]);
#pragma unroll
          for (int g = 0; g < 4; ++g)
#pragma unroll
            for (int r = 0; r < 4; ++r) gf4[g][r] += xv[r][d] * w4[g];
        }
#pragma unroll
        for (int r = 0; r < 4; ++r) {
          float iv = sigm(gf4[0][r]);
          float fv = sigm(gf4[1][r]);
          float gv = tanh_(gf4[2][r]);
          float ov = sigm(gf4[3][r]);
          c0r[cc][r] = fv * c0r[cc][r] + iv * gv;
          char hi, lo;
          q8pair(ov * tanh_(c0r[cc][r]), wq0, &hi, &lo);
          int off = ((16 + 2 * w + cc) * 16 + myrow + r) * 16 + l15;
          Xch[off] = hi; Xcl[off] = lo;
        }
      }
    }
    __syncthreads();   // (b) h0' visible

    // ================= layer 1: [h1|h0'] @ W1 (64 tiles, slot = (j+2)%3) ====
#pragma unroll
    for (int i = 0; i < 8; ++i) { acch[i] = zi; accl[i] = zi; }
    {
      v4i ah, al;
#pragma unroll
      for (int j = 0; j < 64; ++j) {
        const int i = j & 7, s = (j + 2) % 3;
        if (i == 0) { int kcr = ((j >> 3) + rot1) & 7; ah = A1VH(kcr); al = A1VL(kcr); }
        wait_vmcnt<2>();
        v4i bb = __builtin_bit_cast(v4i, ring[w][s][lane]);
        acch[i] = __builtin_amdgcn_mfma_i32_16x16x64_i8(ah, bb, acch[i], 0, 0, 0);
        accl[i] = __builtin_amdgcn_mfma_i32_16x16x64_i8(al, bb, accl[i], 0, 0, 0);
        const int jn = j + 3;
        if (jn < 64) {
          int kcr = ((jn >> 3) + rot1) & 7;
          async_copy16(gp1 + ((size_t)kcr << 16) + ((size_t)(jn & 7) << 10), &ring[w][s][0]);
        } else {           // next step's L0 prologue tiles 0..2 -> slots 0..2
          int j0 = jn - 64;
          async_copy16(gp0 + ((size_t)rot0 << 16) + ((size_t)j0 << 10), &ring[w][s][0]);
        }
      }
    }
    __syncthreads();   // (c) L1 A-reads done; next L0 prologue drained

    // ---- cell 1 ----
#pragma unroll
    for (int cc = 0; cc < 2; ++cc)
#pragma unroll
      for (int r = 0; r < 4; ++r) {
        float di = ((float)acch[0 + cc][r] + (float)accl[0 + cc][r] * (1.f / 254.f));
        float df = ((float)acch[2 + cc][r] + (float)accl[2 + cc][r] * (1.f / 254.f));
        float dg = ((float)acch[4 + cc][r] + (float)accl[4 + cc][r] * (1.f / 254.f));
        float dv = ((float)acch[6 + cc][r] + (float)accl[6 + cc][r] * (1.f / 254.f));
        float iv = sigm(di * csA1[0 + cc] * sc1 + bA1[0 + cc]);
        float fv = sigm(df * csA1[2 + cc] * sc1 + bA1[2 + cc]);
        float gv = tanh_(dg * csA1[4 + cc] * sc1 + bA1[4 + cc]);
        float ov = sigm(dv * csA1[6 + cc] * sc1 + bA1[6 + cc]);
        c1r[cc][r] = fv * c1r[cc][r] + iv * gv;
        float h = ov * tanh_(c1r[cc][r]);
        char hi, lo;
        q8pair(h, 127.f, &hi, &lo);     // h1 always stored at scale 127
        int off = ((2 * w + cc) * 16 + myrow + r) * 16 + l15;
        Xch[off] = hi; Xcl[off] = lo;
      }
    __syncthreads();   // (d) h1 visible

    // ---- out projection from X hi/lo planes + shfl reduce over opq ----
    {
      float s_ = 0.f;
#pragma unroll
      for (int i = 0; i < 16; ++i) {
        int off = (i * 16 + opr) * 16 + opq * 4;
        int hb = *(const int*)(Xch + off);
        int lb = *(const int*)(Xcl + off);
        ushort4 wx = *(const ushort4*)&woutT[opd * WSTR + i * 16 + opq * 4];
        const unsigned short* wp = (const unsigned short*)&wx;
#pragma unroll
        for (int q = 0; q < 4; ++q) {
          float hv = (float)((char)(hb >> (8 * q)))
                   + (float)((char)(lb >> (8 * q))) * (1.f / 254.f);
          s_ += hv * bf2f(wp[q]);
        }
      }
      s_ += __shfl_xor(s_, 1);
      s_ += __shfl_xor(s_, 2);
      if (opq == 0)
        out[(size_t)(b0 + opr) * (TSTEPS * DDIM) + (size_t)t * DDIM + opd] =
            s_ * (1.f / 127.f) + bo_out;
    }
    // next iteration's barrier (1) separates these reads/stores from rewrites
  }
#undef A0VH
#undef A0VL
#undef A1VH
#undef A1VL
}

extern "C" void kernel_launch(void* const* d_in, const int* in_sizes, int n_in,
                              void* d_out, int out_size, void* d_ws, size_t ws_size,
                              hipStream_t stream) {
  const float* z    = (const float*)d_in[0];
  const float* tgt  = (const float*)d_in[1];
  const float* Wfh  = (const float*)d_in[2];
  const float* bfh  = (const float*)d_in[3];
  const float* Wfc  = (const float*)d_in[4];
  const float* bfc  = (const float*)d_in[5];
  const float* Wih0 = (const float*)d_in[6];
  const float* Whh0 = (const float*)d_in[7];
  const float* bih0 = (const float*)d_in[8];
  const float* bhh0 = (const float*)d_in[9];
  const float* Wih1 = (const float*)d_in[10];
  const float* Whh1 = (const float*)d_in[11];
  const float* bih1 = (const float*)d_in[12];
  const float* bhh1 = (const float*)d_in[13];
  const float* Wout = (const float*)d_in[14];
  const float* bout = (const float*)d_in[15];

  // ws layout (bytes), total ~7.09 MB
  char* ws = (char*)d_ws;
  char*  p0   = ws;                                  // 262,144
  char*  p1   = ws + 262144;                         // 524,288
  char*  h0h  = ws + 786432;                         // 524,288
  char*  h0l  = ws + 1310720;                        // 524,288
  char*  h1h  = ws + 1835008;                        // 524,288
  char*  h1l  = ws + 2359296;                        // 524,288
  float* c0s  = (float*)(ws + 2883584);              // 2,097,152
  float* c1s  = (float*)(ws + 4980736);              // 2,097,152
  float* cs0  = (float*)(ws + 7077888);              // 4,096
  float* qs0  = (float*)(ws + 7081984);              // 4,096
  float* cs1  = (float*)(ws + 7086080);              // 4,096
  float* qs1  = (float*)(ws + 7090176);              // 4,096

  hipLaunchKernelGGL(init_state, dim3(BSZ * HDIM / 256), dim3(256), 0, stream,
                     z, Wfh, bfh, Wfc, bfc, h0h, h0l, h1h, h1l, c0s, c1s);
  hipLaunchKernelGGL(col_scales, dim3(8), dim3(256), 0, stream,
                     Whh0, Wih1, Whh1, cs0, qs0, cs1, qs1);
  hipLaunchKernelGGL(pack_i8, dim3(192), dim3(256), 0, stream,
                     Whh0, Wih1, Whh1, qs0, qs1, p0, p1);
  hipLaunchKernelGGL(lstm_run, dim3(NWG), dim3(NTH), 0, stream,
                     tgt, p0, p1, bih0, bhh0, bih1, bhh1, Wih0, Wout, bout,
                     h0h, h0l, h1h, h1l, c0s, c1s, cs0, cs1, (float*)d_out);
}

// Round 8
// 3549.744 us; speedup vs baseline: 2.2466x; 2.2466x over previous
//
#include <hip/hip_runtime.h>
#include <cstddef>
#include <cstdint>

// 2-layer LSTM decoder, B=2048, Z=64, H=256, D=8, T=250. fp32 in/out.
//
// R8 = R7 numerics (i8 hi/lo, absmax 1.95e-3) with arch-VGPR pressure removed
// so the allocator's 128-arch cap is never exceeded (R5-R7: every spilled reg
// became per-step scratch reloads -> GBs of HBM fetch + L2 thrash).
//  - Weights repacked per-wave-contiguous: stream addr = base + j*1024,
//    linear, no rotation -> scalar strength reduction, no address VGPR army.
//  - j-loops partially unrolled (8), not fully.
//  - cell-0 streams x/Wih0 from LDS per-quad (no xv[32] preload); Wih0 stored
//    transposed col-major bf16 for ushort4 reads.
//  - Ring transport identical to R7 (3 slots/wave, vmcnt(2), cross-phase
//    slot continuity). LDS ~60.6 KB.

#define BSZ    2048
#define ZDIM   64
#define HDIM   256
#define DDIM   8
#define TSTEPS 250
#define ROWS   16
#define NWG    (BSZ / ROWS)   // 128
#define NTH    512            // 8 waves
#define G4     1024
#define WSTR   264            // woutT row stride (shorts)

typedef __attribute__((ext_vector_type(4))) int v4i;

__device__ __forceinline__ unsigned short f2bf(float x) {   // RNE f32->bf16
  union { float f; unsigned u; } v; v.f = x;
  unsigned r = v.u + 0x7fff + ((v.u >> 16) & 1);
  return (unsigned short)(r >> 16);
}
__device__ __forceinline__ float bf2f(unsigned short b) {
  union { unsigned u; float f; } v; v.u = (unsigned)b << 16; return v.f;
}
__device__ __forceinline__ float fexp2(float x) { return __builtin_amdgcn_exp2f(x); }
__device__ __forceinline__ float frcp(float x)  { return __builtin_amdgcn_rcpf(x); }
__device__ __forceinline__ float sigm(float x)  { return frcp(1.f + fexp2(-1.44269504f * x)); }
__device__ __forceinline__ float tanh_(float x) { return 2.f * frcp(1.f + fexp2(-2.88539008f * x)) - 1.f; }
__device__ __forceinline__ char q8(float x, float s) {
  float v = fminf(fmaxf(x * s, -127.f), 127.f);
  return (char)(int)__builtin_rintf(v);
}
// h*s split into hi + lo/254 (lo in [-127,127] exactly since 0.5*254=127)
__device__ __forceinline__ void q8pair(float h, float s, char* hi, char* lo) {
  float hs = fminf(fmaxf(h * s, -127.f), 127.f);
  float hq = __builtin_rintf(hs);
  *hi = (char)(int)hq;
  *lo = (char)(int)__builtin_rintf((hs - hq) * 254.f);
}

// async 16B/lane global->LDS DMA (verified R3/R7): lands at ldsbase + lane*16
__device__ __forceinline__ void async_copy16(const void* g, void* l) {
  __builtin_amdgcn_global_load_lds(
      reinterpret_cast<const __attribute__((address_space(1))) unsigned int*>(
          reinterpret_cast<uintptr_t>(g)),
      reinterpret_cast<__attribute__((address_space(3))) unsigned int*>(
          reinterpret_cast<uintptr_t>(l)),
      16, 0, 0);
}
// s_waitcnt vmcnt(N) only
template <int N>
__device__ __forceinline__ void wait_vmcnt() {
  __builtin_amdgcn_s_waitcnt((N & 15) | (7 << 4) | (15 << 8) | (((N >> 4) & 3) << 14));
}

// ---------------- initial state (mapping verified R1-R7) ----------------
__global__ void init_state(const float* __restrict__ z,
                           const float* __restrict__ Wfh, const float* __restrict__ bfh,
                           const float* __restrict__ Wfc, const float* __restrict__ bfc,
                           char* __restrict__ h0h, char* __restrict__ h0l,
                           char* __restrict__ h1h, char* __restrict__ h1l,
                           float* __restrict__ c0s, float* __restrict__ c1s)
{
  int idx = blockIdx.x * 256 + threadIdx.x;
  int b = idx >> 8;
  int j = idx & 255;
  int col = ((b & 1) << 8) | j;
  const float* z0 = z + (size_t)(b >> 1) * ZDIM;
  const float* z1 = z + (size_t)(1024 + (b >> 1)) * ZDIM;
  float h0 = bfh[col], c0v = bfc[col], h1 = bfh[col], c1v = bfc[col];
  for (int k = 0; k < ZDIM; ++k) {
    float wh = Wfh[k * 512 + col];
    float wc = Wfc[k * 512 + col];
    float a = z0[k], bb = z1[k];
    h0  += a * wh;  c0v += a * wc;
    h1  += bb * wh; c1v += bb * wc;
  }
  char hi, lo;
  q8pair(h0, 31.75f, &hi, &lo); h0h[idx] = hi; h0l[idx] = lo;
  q8pair(h1, 31.75f, &hi, &lo); h1h[idx] = hi; h1l[idx] = lo;
  c0s[idx] = c0v; c1s[idx] = c1v;
}

// ---------------- per-output-column scales (unchanged) ----------------
__global__ void col_scales(const float* __restrict__ Whh0,
                           const float* __restrict__ Wih1, const float* __restrict__ Whh1,
                           float* __restrict__ cs0, float* __restrict__ qs0,
                           float* __restrict__ cs1, float* __restrict__ qs1)
{
  int c = blockIdx.x * 256 + threadIdx.x;   // 0..2047
  if (c < 1024) {
    float m = 0.f;
    for (int k = 0; k < 256; ++k) m = fmaxf(m, fabsf(Whh0[(size_t)k * G4 + c]));
    cs0[c] = m * (1.f / 16129.f);
    qs0[c] = 127.f / m;
  } else {
    c -= 1024;
    float m = 0.f;
    for (int k = 0; k < 256; ++k) m = fmaxf(m, fabsf(Whh1[(size_t)k * G4 + c]));
    for (int k = 0; k < 256; ++k) m = fmaxf(m, fabsf(Wih1[(size_t)k * G4 + c]));
    cs1[c] = m * (1.f / 16129.f);
    qs1[c] = 127.f / m;
  }
}

// ---- i8 weight pack: PER-WAVE-CONTIGUOUS linear stream order ----
// B-frag (16x16x64 i8, verified R4-R7): lane l holds W[k=kc*64+(l>>4)*16+j][n].
// tile i: gate g=i>>1, cc=i&1, ntile = g*16 + 2*w + cc.
// p0: offset = ((w*4 + kc)*8 + i)*1024   (layer0: K=256 -> 4 kc groups)
// p1: offset = ((w*8 + kc)*8 + i)*1024   (layer1: K=512 -> 8 kc groups)
// Layer0 K: Whh0. Layer1 K: 0..255 Whh1 (h1 first) | 256..511 Wih1 (h0').
__global__ void pack_i8(const float* __restrict__ Whh0,
                        const float* __restrict__ Wih1, const float* __restrict__ Whh1,
                        const float* __restrict__ qs0, const float* __restrict__ qs1,
                        char* __restrict__ p0, char* __restrict__ p1)
{
  int tt   = blockIdx.x * 4 + (threadIdx.x >> 6);   // 0..767
  int lane = threadIdx.x & 63;
  int l15 = lane & 15, lq = lane >> 4;
  union { char c[16]; uint4 u; } v;
  if (tt < 256) {                                   // layer0: w*4+kc, i
    int w = tt >> 5, kc = (tt >> 3) & 3, i = tt & 7;
    int nt = (i >> 1) * 16 + 2 * w + (i & 1);
    int col = nt * 16 + l15;
    float q = qs0[col];
    for (int j = 0; j < 16; ++j) {
      int k = kc * 64 + lq * 16 + j;
      v.c[j] = q8(Whh0[(size_t)k * G4 + col], q);
    }
    *(uint4*)(p0 + (size_t)tt * 1024 + lane * 16) = v.u;
  } else {                                          // layer1: w*8+kc, i
    int t1 = tt - 256;
    int w = t1 >> 6, kc = (t1 >> 3) & 7, i = t1 & 7;
    int nt = (i >> 1) * 16 + 2 * w + (i & 1);
    int col = nt * 16 + l15;
    float q = qs1[col];
    for (int j = 0; j < 16; ++j) {
      int k = kc * 64 + lq * 16 + j;
      float wv = (k < 256) ? Whh1[(size_t)k * G4 + col]
                           : Wih1[(size_t)(k - 256) * G4 + col];
      v.c[j] = q8(wv, q);
    }
    *(uint4*)(p1 + (size_t)t1 * 1024 + lane * 16) = v.u;
  }
}

// ---------------- persistent LSTM kernel ----------------
__global__ __launch_bounds__(NTH, 1) void lstm_run(
    const float* __restrict__ target,
    const char* __restrict__ p0, const char* __restrict__ p1,
    const float* __restrict__ bih0, const float* __restrict__ bhh0,
    const float* __restrict__ bih1, const float* __restrict__ bhh1,
    const float* __restrict__ Wih0,            // [8,1024] fp32 -> bf16 LDS (transposed)
    const float* __restrict__ Wout, const float* __restrict__ bout,
    const char* __restrict__ h0h, const char* __restrict__ h0l,
    const char* __restrict__ h1h, const char* __restrict__ h1l,
    const float* __restrict__ c0s, const float* __restrict__ c1s,
    const float* __restrict__ cs0, const float* __restrict__ cs1,
    float* __restrict__ out)
{
  __shared__ uint4 ring[8][3][64];                 // 24 KB: per-wave 3x1KB slots
  __shared__ uint4 X4h[32 * 16];                   // 8 KB (blk 0..15 h1, 16..31 h0)
  __shared__ uint4 X4l[32 * 16];                   // 8 KB
  __shared__ unsigned short wih0p[G4 * DDIM];      // 16 KB bf16, [col][d] (transposed)
  __shared__ unsigned short woutT[8 * WSTR];       // 4.1 KB bf16
  __shared__ float x_lds[16 * 8];                  // 0.5 KB  (total ~60.6 KB)

  const int tid  = threadIdx.x;
  const int w    = tid >> 6;
  const int lane = tid & 63;
  const int l15  = lane & 15;
  const int lq   = lane >> 4;
  const int b0   = blockIdx.x * ROWS;
  char* Xch = (char*)X4h;
  char* Xcl = (char*)X4l;

  // ---- one-time staging ----
  {
    int m = tid & 15, blk = tid >> 4;              // 32 blks x 16 m
    const char* sh = (blk < 16) ? h1h : h0h;
    const char* sl = (blk < 16) ? h1l : h0l;
    int jblk = blk & 15;
    X4h[blk * 16 + m] = *(const uint4*)(sh + (size_t)(b0 + m) * HDIM + jblk * 16);
    X4l[blk * 16 + m] = *(const uint4*)(sl + (size_t)(b0 + m) * HDIM + jblk * 16);
  }
  for (int i = tid; i < DDIM * G4; i += NTH) {     // transpose: [d][col] -> [col][d]
    int d = i >> 10, col = i & 1023;
    wih0p[col * DDIM + d] = f2bf(Wih0[i]);
  }
  for (int i = tid; i < HDIM * DDIM; i += NTH) {
    int k = i >> 3, d = i & 7;
    woutT[d * WSTR + k] = f2bf(Wout[i]);
  }

  const int myrow = lq * 4;
  const int jc0   = 32 * w + l15;
  float c0r[2][4], c1r[2][4];
  float bA0[8], bA1[8], csA0[8], csA1[8];          // flat [g*2+cc]
#pragma unroll
  for (int i = 0; i < 8; ++i) {
    int col = (i >> 1) * 256 + jc0 + 16 * (i & 1);
    bA0[i]  = bih0[col] + bhh0[col];
    bA1[i]  = bih1[col] + bhh1[col];
    csA0[i] = cs0[col];
    csA1[i] = cs1[col];
  }
#pragma unroll
  for (int cc = 0; cc < 2; ++cc) {
    int j = jc0 + cc * 16;
#pragma unroll
    for (int r = 0; r < 4; ++r) {
      c0r[cc][r] = c0s[(size_t)(b0 + myrow + r) * HDIM + j];
      c1r[cc][r] = c1s[(size_t)(b0 + myrow + r) * HDIM + j];
    }
  }
  const int opr = tid >> 5, opd = (tid >> 2) & 7, opq = tid & 3;
  const float bo_out = bout[opd];

  // per-lane weight stream bases; tile j at base + j*1024 (LINEAR)
  const char* gp0 = p0 + (size_t)w * 32768 + lane * 16;
  const char* gp1 = p1 + (size_t)w * 65536 + lane * 16;

#define A0VH(KC) __builtin_bit_cast(v4i, X4h[(16 + (KC) * 4 + lq) * 16 + l15])
#define A0VL(KC) __builtin_bit_cast(v4i, X4l[(16 + (KC) * 4 + lq) * 16 + l15])
#define A1VH(KC) __builtin_bit_cast(v4i, X4h[((KC) * 4 + lq) * 16 + l15])
#define A1VL(KC) __builtin_bit_cast(v4i, X4l[((KC) * 4 + lq) * 16 + l15])

  // initial prologue: L0 tiles 0,1,2 -> slots 0,1,2
  async_copy16(gp0,        &ring[w][0][0]);
  async_copy16(gp0 + 1024, &ring[w][1][0]);
  async_copy16(gp0 + 2048, &ring[w][2][0]);

  __syncthreads();

#pragma unroll 1
  for (int t = 0; t < TSTEPS; ++t) {
    // ---- teacher-forced input (fp32) ----
    if (tid < 128) {
      int m = tid >> 3, d = tid & 7;
      x_lds[m * 8 + d] = (t == 0) ? 0.f
          : target[(size_t)(b0 + m) * (TSTEPS * DDIM) + (size_t)(t - 1) * DDIM + d];
    }
    __syncthreads();   // (1) x visible; barrier drain -> slots 0..2 landed

    const float sc0 = (t <= 1) ? 4.f : 1.f;
    const float sc1 = (t == 0) ? 4.f : 1.f;
    const float wq0 = (t == 0) ? 31.75f : 127.f;

    v4i acch[8], accl[8];
    const v4i zi = {0, 0, 0, 0};

    // ============ layer 0: h0 @ Whh0 (32 tiles, slot = j%3) ============
#pragma unroll
    for (int i = 0; i < 8; ++i) { acch[i] = zi; accl[i] = zi; }
    {
      v4i ah, al;
#pragma unroll 8
      for (int j = 0; j < 32; ++j) {
        const int i = j & 7, s = j % 3;
        if (i == 0) { int kc = j >> 3; ah = A0VH(kc); al = A0VL(kc); }
        wait_vmcnt<2>();
        v4i bb = __builtin_bit_cast(v4i, ring[w][s][lane]);
        acch[i] = __builtin_amdgcn_mfma_i32_16x16x64_i8(ah, bb, acch[i], 0, 0, 0);
        accl[i] = __builtin_amdgcn_mfma_i32_16x16x64_i8(al, bb, accl[i], 0, 0, 0);
        const int jn = j + 3;
        if (jn < 32) async_copy16(gp0 + (size_t)jn * 1024, &ring[w][s][0]);
        else         async_copy16(gp1 + (size_t)(jn - 32) * 1024, &ring[w][s][0]);
      }
    }
    __syncthreads();   // (a) L0 A-reads done; L1 prologue landed

    // ---- cell 0: dequant + fp32 x-path (streamed from LDS) ----
#pragma unroll
    for (int cc = 0; cc < 2; ++cc) {
      float gf4[4][4];
#pragma unroll
      for (int g = 0; g < 4; ++g) {
        int i = g * 2 + cc;
        float cs = csA0[i] * sc0;
#pragma unroll
        for (int r = 0; r < 4; ++r)
          gf4[g][r] = ((float)acch[i][r] + (float)accl[i][r] * (1.f / 254.f)) * cs + bA0[i];
      }
#pragma unroll
      for (int q = 0; q < 2; ++q) {              // d-quads: d = q*4 .. q*4+3
        ushort4 wv[4];
#pragma unroll
        for (int g = 0; g < 4; ++g)
          wv[g] = *(const ushort4*)&wih0p[(g * 256 + jc0 + 16 * cc) * DDIM + q * 4];
#pragma unroll
        for (int r = 0; r < 4; ++r) {
          float4 xr = *(const float4*)&x_lds[(myrow + r) * 8 + q * 4];
          const float* xp = (const float*)&xr;
#pragma unroll
          for (int g = 0; g < 4; ++g) {
            const unsigned short* wp = (const unsigned short*)&wv[g];
            gf4[g][r] += xp[0] * bf2f(wp[0]) + xp[1] * bf2f(wp[1])
                       + xp[2] * bf2f(wp[2]) + xp[3] * bf2f(wp[3]);
          }
        }
      }
#pragma unroll
      for (int r = 0; r < 4; ++r) {
        float iv = sigm(gf4[0][r]);
        float fv = sigm(gf4[1][r]);
        float gv = tanh_(gf4[2][r]);
        float ov = sigm(gf4[3][r]);
        c0r[cc][r] = fv * c0r[cc][r] + iv * gv;
        char hi, lo;
        q8pair(ov * tanh_(c0r[cc][r]), wq0, &hi, &lo);
        int off = ((16 + 2 * w + cc) * 16 + myrow + r) * 16 + l15;
        Xch[off] = hi; Xcl[off] = lo;
      }
    }
    __syncthreads();   // (b) h0' visible

    // ============ layer 1: [h1|h0'] @ W1 (64 tiles, slot = (j+2)%3) ============
#pragma unroll
    for (int i = 0; i < 8; ++i) { acch[i] = zi; accl[i] = zi; }
    {
      v4i ah, al;
#pragma unroll 8
      for (int j = 0; j < 64; ++j) {
        const int i = j & 7, s = (j + 2) % 3;
        if (i == 0) { int kc = j >> 3; ah = A1VH(kc); al = A1VL(kc); }
        wait_vmcnt<2>();
        v4i bb = __builtin_bit_cast(v4i, ring[w][s][lane]);
        acch[i] = __builtin_amdgcn_mfma_i32_16x16x64_i8(ah, bb, acch[i], 0, 0, 0);
        accl[i] = __builtin_amdgcn_mfma_i32_16x16x64_i8(al, bb, accl[i], 0, 0, 0);
        const int jn = j + 3;
        if (jn < 64) async_copy16(gp1 + (size_t)jn * 1024, &ring[w][s][0]);
        else         async_copy16(gp0 + (size_t)(jn - 64) * 1024, &ring[w][s][0]);
      }
    }
    __syncthreads();   // (c) L1 A-reads done; next step's L0 prologue landed

    // ---- cell 1 ----
#pragma unroll
    for (int cc = 0; cc < 2; ++cc)
#pragma unroll
      for (int r = 0; r < 4; ++r) {
        float di = ((float)acch[0 + cc][r] + (float)accl[0 + cc][r] * (1.f / 254.f));
        float df = ((float)acch[2 + cc][r] + (float)accl[2 + cc][r] * (1.f / 254.f));
        float dg = ((float)acch[4 + cc][r] + (float)accl[4 + cc][r] * (1.f / 254.f));
        float dv = ((float)acch[6 + cc][r] + (float)accl[6 + cc][r] * (1.f / 254.f));
        float iv = sigm(di * csA1[0 + cc] * sc1 + bA1[0 + cc]);
        float fv = sigm(df * csA1[2 + cc] * sc1 + bA1[2 + cc]);
        float gv = tanh_(dg * csA1[4 + cc] * sc1 + bA1[4 + cc]);
        float ov = sigm(dv * csA1[6 + cc] * sc1 + bA1[6 + cc]);
        c1r[cc][r] = fv * c1r[cc][r] + iv * gv;
        float h = ov * tanh_(c1r[cc][r]);
        char hi, lo;
        q8pair(h, 127.f, &hi, &lo);
        int off = ((2 * w + cc) * 16 + myrow + r) * 16 + l15;
        Xch[off] = hi; Xcl[off] = lo;
      }
    __syncthreads();   // (d) h1 visible

    // ---- out projection from X hi/lo planes + shfl reduce over opq ----
    {
      float s_ = 0.f;
#pragma unroll
      for (int i = 0; i < 16; ++i) {
        int off = (i * 16 + opr) * 16 + opq * 4;
        int hb = *(const int*)(Xch + off);
        int lb = *(const int*)(Xcl + off);
        ushort4 wx = *(const ushort4*)&woutT[opd * WSTR + i * 16 + opq * 4];
        const unsigned short* wp = (const unsigned short*)&wx;
#pragma unroll
        for (int q = 0; q < 4; ++q) {
          float hv = (float)((char)(hb >> (8 * q)))
                   + (float)((char)(lb >> (8 * q))) * (1.f / 254.f);
          s_ += hv * bf2f(wp[q]);
        }
      }
      s_ += __shfl_xor(s_, 1);
      s_ += __shfl_xor(s_, 2);
      if (opq == 0)
        out[(size_t)(b0 + opr) * (TSTEPS * DDIM) + (size_t)t * DDIM + opd] =
            s_ * (1.f / 127.f) + bo_out;
    }
    // next iteration's barrier (1) separates these reads/stores from rewrites
  }
#undef A0VH
#undef A0VL
#undef A1VH
#undef A1VL
}

extern "C" void kernel_launch(void* const* d_in, const int* in_sizes, int n_in,
                              void* d_out, int out_size, void* d_ws, size_t ws_size,
                              hipStream_t stream) {
  const float* z    = (const float*)d_in[0];
  const float* tgt  = (const float*)d_in[1];
  const float* Wfh  = (const float*)d_in[2];
  const float* bfh  = (const float*)d_in[3];
  const float* Wfc  = (const float*)d_in[4];
  const float* bfc  = (const float*)d_in[5];
  const float* Wih0 = (const float*)d_in[6];
  const float* Whh0 = (const float*)d_in[7];
  const float* bih0 = (const float*)d_in[8];
  const float* bhh0 = (const float*)d_in[9];
  const float* Wih1 = (const float*)d_in[10];
  const float* Whh1 = (const float*)d_in[11];
  const float* bih1 = (const float*)d_in[12];
  const float* bhh1 = (const float*)d_in[13];
  const float* Wout = (const float*)d_in[14];
  const float* bout = (const float*)d_in[15];

  // ws layout (bytes), total ~7.09 MB
  char* ws = (char*)d_ws;
  char*  p0   = ws;                                  // 262,144
  char*  p1   = ws + 262144;                         // 524,288
  char*  h0h  = ws + 786432;                         // 524,288
  char*  h0l  = ws + 1310720;                        // 524,288
  char*  h1h  = ws + 1835008;                        // 524,288
  char*  h1l  = ws + 2359296;                        // 524,288
  float* c0s  = (float*)(ws + 2883584);              // 2,097,152
  float* c1s  = (float*)(ws + 4980736);              // 2,097,152
  float* cs0  = (float*)(ws + 7077888);              // 4,096
  float* qs0  = (float*)(ws + 7081984);              // 4,096
  float* cs1  = (float*)(ws + 7086080);              // 4,096
  float* qs1  = (float*)(ws + 7090176);              // 4,096

  hipLaunchKernelGGL(init_state, dim3(BSZ * HDIM / 256), dim3(256), 0, stream,
                     z, Wfh, bfh, Wfc, bfc, h0h, h0l, h1h, h1l, c0s, c1s);
  hipLaunchKernelGGL(col_scales, dim3(8), dim3(256), 0, stream,
                     Whh0, Wih1, Whh1, cs0, qs0, cs1, qs1);
  hipLaunchKernelGGL(pack_i8, dim3(192), dim3(256), 0, stream,
                     Whh0, Wih1, Whh1, qs0, qs1, p0, p1);
  hipLaunchKernelGGL(lstm_run, dim3(NWG), dim3(NTH), 0, stream,
                     tgt, p0, p1, bih0, bhh0, bih1, bhh1, Wih0, Wout, bout,
                     h0h, h0l, h1h, h1l, c0s, c1s, cs0, cs1, (float*)d_out);
}

// Round 9
// 3055.249 us; speedup vs baseline: 2.6102x; 1.1619x over previous
//
#include <hip/hip_runtime.h>
#include <cstddef>
#include <cstdint>

// 2-layer LSTM decoder, B=2048, Z=64, H=256, D=8, T=250. fp32 in/out.
//
// R9 = R8 (i8 hi/lo ring-streamed, no spills, 3.55 ms) with the serial VALU
// phases slimmed and the ring deepened:
//  - x-path Wih0 columns held in 64 fp32 VGPRs/thread (loaded once) ->
//    cell-0 loses ~900 convert/inst per thread-step; wih0p LDS freed (16 KB).
//  - out-proj reads a bf16 h1f plane (written in cell-1) -> ~150 inst.
//  - ring 4 slots/wave (32 KB), vmcnt(3); 32 and 64 tiles both divisible by
//    4 -> slot = j&3 in every phase, cross-phase continuity preserved.
// LDS 62.3 KB. Arch VGPR demand ~180 < 256 cap (1 WG/CU, 2 waves/SIMD).

#define BSZ    2048
#define ZDIM   64
#define HDIM   256
#define DDIM   8
#define TSTEPS 250
#define ROWS   16
#define NWG    (BSZ / ROWS)   // 128
#define NTH    512            // 8 waves
#define G4     1024
#define WSTR   264            // h1f/woutT row stride (shorts)

typedef __attribute__((ext_vector_type(4))) int v4i;

__device__ __forceinline__ unsigned short f2bf(float x) {   // RNE f32->bf16
  union { float f; unsigned u; } v; v.f = x;
  unsigned r = v.u + 0x7fff + ((v.u >> 16) & 1);
  return (unsigned short)(r >> 16);
}
__device__ __forceinline__ float bf2f(unsigned short b) {
  union { unsigned u; float f; } v; v.u = (unsigned)b << 16; return v.f;
}
__device__ __forceinline__ float fexp2(float x) { return __builtin_amdgcn_exp2f(x); }
__device__ __forceinline__ float frcp(float x)  { return __builtin_amdgcn_rcpf(x); }
__device__ __forceinline__ float sigm(float x)  { return frcp(1.f + fexp2(-1.44269504f * x)); }
__device__ __forceinline__ float tanh_(float x) { return 2.f * frcp(1.f + fexp2(-2.88539008f * x)) - 1.f; }
__device__ __forceinline__ char q8(float x, float s) {
  float v = fminf(fmaxf(x * s, -127.f), 127.f);
  return (char)(int)__builtin_rintf(v);
}
// h*s split into hi + lo/254 (lo in [-127,127] exactly since 0.5*254=127)
__device__ __forceinline__ void q8pair(float h, float s, char* hi, char* lo) {
  float hs = fminf(fmaxf(h * s, -127.f), 127.f);
  float hq = __builtin_rintf(hs);
  *hi = (char)(int)hq;
  *lo = (char)(int)__builtin_rintf((hs - hq) * 254.f);
}

// async 16B/lane global->LDS DMA (verified R3/R7/R8)
__device__ __forceinline__ void async_copy16(const void* g, void* l) {
  __builtin_amdgcn_global_load_lds(
      reinterpret_cast<const __attribute__((address_space(1))) unsigned int*>(
          reinterpret_cast<uintptr_t>(g)),
      reinterpret_cast<__attribute__((address_space(3))) unsigned int*>(
          reinterpret_cast<uintptr_t>(l)),
      16, 0, 0);
}
template <int N>
__device__ __forceinline__ void wait_vmcnt() {
  __builtin_amdgcn_s_waitcnt((N & 15) | (7 << 4) | (15 << 8) | (((N >> 4) & 3) << 14));
}

// ---------------- initial state (mapping verified R1-R8) ----------------
__global__ void init_state(const float* __restrict__ z,
                           const float* __restrict__ Wfh, const float* __restrict__ bfh,
                           const float* __restrict__ Wfc, const float* __restrict__ bfc,
                           char* __restrict__ h0h, char* __restrict__ h0l,
                           char* __restrict__ h1h, char* __restrict__ h1l,
                           float* __restrict__ c0s, float* __restrict__ c1s)
{
  int idx = blockIdx.x * 256 + threadIdx.x;
  int b = idx >> 8;
  int j = idx & 255;
  int col = ((b & 1) << 8) | j;
  const float* z0 = z + (size_t)(b >> 1) * ZDIM;
  const float* z1 = z + (size_t)(1024 + (b >> 1)) * ZDIM;
  float h0 = bfh[col], c0v = bfc[col], h1 = bfh[col], c1v = bfc[col];
  for (int k = 0; k < ZDIM; ++k) {
    float wh = Wfh[k * 512 + col];
    float wc = Wfc[k * 512 + col];
    float a = z0[k], bb = z1[k];
    h0  += a * wh;  c0v += a * wc;
    h1  += bb * wh; c1v += bb * wc;
  }
  char hi, lo;
  q8pair(h0, 31.75f, &hi, &lo); h0h[idx] = hi; h0l[idx] = lo;
  q8pair(h1, 31.75f, &hi, &lo); h1h[idx] = hi; h1l[idx] = lo;
  c0s[idx] = c0v; c1s[idx] = c1v;
}

// ---------------- per-output-column scales (unchanged) ----------------
__global__ void col_scales(const float* __restrict__ Whh0,
                           const float* __restrict__ Wih1, const float* __restrict__ Whh1,
                           float* __restrict__ cs0, float* __restrict__ qs0,
                           float* __restrict__ cs1, float* __restrict__ qs1)
{
  int c = blockIdx.x * 256 + threadIdx.x;   // 0..2047
  if (c < 1024) {
    float m = 0.f;
    for (int k = 0; k < 256; ++k) m = fmaxf(m, fabsf(Whh0[(size_t)k * G4 + c]));
    cs0[c] = m * (1.f / 16129.f);
    qs0[c] = 127.f / m;
  } else {
    c -= 1024;
    float m = 0.f;
    for (int k = 0; k < 256; ++k) m = fmaxf(m, fabsf(Whh1[(size_t)k * G4 + c]));
    for (int k = 0; k < 256; ++k) m = fmaxf(m, fabsf(Wih1[(size_t)k * G4 + c]));
    cs1[c] = m * (1.f / 16129.f);
    qs1[c] = 127.f / m;
  }
}

// ---- i8 weight pack: per-wave-contiguous linear stream (verified R8) ----
__global__ void pack_i8(const float* __restrict__ Whh0,
                        const float* __restrict__ Wih1, const float* __restrict__ Whh1,
                        const float* __restrict__ qs0, const float* __restrict__ qs1,
                        char* __restrict__ p0, char* __restrict__ p1)
{
  int tt   = blockIdx.x * 4 + (threadIdx.x >> 6);   // 0..767
  int lane = threadIdx.x & 63;
  int l15 = lane & 15, lq = lane >> 4;
  union { char c[16]; uint4 u; } v;
  if (tt < 256) {                                   // layer0: w*4+kc, i
    int w = tt >> 5, kc = (tt >> 3) & 3, i = tt & 7;
    int nt = (i >> 1) * 16 + 2 * w + (i & 1);
    int col = nt * 16 + l15;
    float q = qs0[col];
    for (int j = 0; j < 16; ++j) {
      int k = kc * 64 + lq * 16 + j;
      v.c[j] = q8(Whh0[(size_t)k * G4 + col], q);
    }
    *(uint4*)(p0 + (size_t)tt * 1024 + lane * 16) = v.u;
  } else {                                          // layer1: w*8+kc, i
    int t1 = tt - 256;
    int w = t1 >> 6, kc = (t1 >> 3) & 7, i = t1 & 7;
    int nt = (i >> 1) * 16 + 2 * w + (i & 1);
    int col = nt * 16 + l15;
    float q = qs1[col];
    for (int j = 0; j < 16; ++j) {
      int k = kc * 64 + lq * 16 + j;
      float wv = (k < 256) ? Whh1[(size_t)k * G4 + col]
                           : Wih1[(size_t)(k - 256) * G4 + col];
      v.c[j] = q8(wv, q);
    }
    *(uint4*)(p1 + (size_t)t1 * 1024 + lane * 16) = v.u;
  }
}

// ---------------- persistent LSTM kernel ----------------
__global__ __launch_bounds__(NTH, 1) void lstm_run(
    const float* __restrict__ target,
    const char* __restrict__ p0, const char* __restrict__ p1,
    const float* __restrict__ bih0, const float* __restrict__ bhh0,
    const float* __restrict__ bih1, const float* __restrict__ bhh1,
    const float* __restrict__ Wih0,            // [8,1024] fp32 -> 64 VGPRs/thread
    const float* __restrict__ Wout, const float* __restrict__ bout,
    const char* __restrict__ h0h, const char* __restrict__ h0l,
    const char* __restrict__ h1h, const char* __restrict__ h1l,
    const float* __restrict__ c0s, const float* __restrict__ c1s,
    const float* __restrict__ cs0, const float* __restrict__ cs1,
    float* __restrict__ out)
{
  __shared__ uint4 ring[8][4][64];                 // 32 KB: per-wave 4x1KB slots
  __shared__ uint4 X4h[32 * 16];                   // 8 KB (blk 0..15 h1, 16..31 h0)
  __shared__ uint4 X4l[32 * 16];                   // 8 KB
  __shared__ unsigned short h1f[16 * WSTR];        // 8.25 KB bf16 h1 (out-proj)
  __shared__ unsigned short woutT[8 * WSTR];       // 4.1 KB bf16
  __shared__ float x_lds[16 * 8];                  // 0.5 KB  (total ~62.3 KB)

  const int tid  = threadIdx.x;
  const int w    = tid >> 6;
  const int lane = tid & 63;
  const int l15  = lane & 15;
  const int lq   = lane >> 4;
  const int b0   = blockIdx.x * ROWS;
  char* Xch = (char*)X4h;
  char* Xcl = (char*)X4l;

  // ---- one-time staging ----
  {
    int m = tid & 15, blk = tid >> 4;              // 32 blks x 16 m
    const char* sh = (blk < 16) ? h1h : h0h;
    const char* sl = (blk < 16) ? h1l : h0l;
    int jblk = blk & 15;
    X4h[blk * 16 + m] = *(const uint4*)(sh + (size_t)(b0 + m) * HDIM + jblk * 16);
    X4l[blk * 16 + m] = *(const uint4*)(sl + (size_t)(b0 + m) * HDIM + jblk * 16);
  }
  for (int i = tid; i < HDIM * DDIM; i += NTH) {
    int k = i >> 3, d = i & 7;
    woutT[d * WSTR + k] = f2bf(Wout[i]);
  }

  const int myrow = lq * 4;
  const int jc0   = 32 * w + l15;
  float c0r[2][4], c1r[2][4];
  float bA0[8], bA1[8], csA0[8], csA1[8];          // flat [g*2+cc]
  float wx[8][8];                                  // Wih0[d][col(i)] in regs
#pragma unroll
  for (int i = 0; i < 8; ++i) {
    int col = (i >> 1) * 256 + jc0 + 16 * (i & 1);
    bA0[i]  = bih0[col] + bhh0[col];
    bA1[i]  = bih1[col] + bhh1[col];
    csA0[i] = cs0[col];
    csA1[i] = cs1[col];
#pragma unroll
    for (int d = 0; d < 8; ++d) wx[i][d] = Wih0[d * G4 + col];
  }
#pragma unroll
  for (int cc = 0; cc < 2; ++cc) {
    int j = jc0 + cc * 16;
#pragma unroll
    for (int r = 0; r < 4; ++r) {
      c0r[cc][r] = c0s[(size_t)(b0 + myrow + r) * HDIM + j];
      c1r[cc][r] = c1s[(size_t)(b0 + myrow + r) * HDIM + j];
    }
  }
  const int opr = tid >> 5, opd = (tid >> 2) & 7, opq = tid & 3;
  const float bo_out = bout[opd];

  // per-lane weight stream bases; tile j at base + j*1024 (linear)
  const char* gp0 = p0 + (size_t)w * 32768 + lane * 16;
  const char* gp1 = p1 + (size_t)w * 65536 + lane * 16;

#define A0VH(KC) __builtin_bit_cast(v4i, X4h[(16 + (KC) * 4 + lq) * 16 + l15])
#define A0VL(KC) __builtin_bit_cast(v4i, X4l[(16 + (KC) * 4 + lq) * 16 + l15])
#define A1VH(KC) __builtin_bit_cast(v4i, X4h[((KC) * 4 + lq) * 16 + l15])
#define A1VL(KC) __builtin_bit_cast(v4i, X4l[((KC) * 4 + lq) * 16 + l15])

  // initial prologue: L0 tiles 0..3 -> slots 0..3
  async_copy16(gp0,        &ring[w][0][0]);
  async_copy16(gp0 + 1024, &ring[w][1][0]);
  async_copy16(gp0 + 2048, &ring[w][2][0]);
  async_copy16(gp0 + 3072, &ring[w][3][0]);

  __syncthreads();

#pragma unroll 1
  for (int t = 0; t < TSTEPS; ++t) {
    // ---- teacher-forced input (fp32) ----
    if (tid < 128) {
      int m = tid >> 3, d = tid & 7;
      x_lds[m * 8 + d] = (t == 0) ? 0.f
          : target[(size_t)(b0 + m) * (TSTEPS * DDIM) + (size_t)(t - 1) * DDIM + d];
    }
    __syncthreads();   // (1) x visible; barrier drain -> slots 0..3 landed

    const float sc0 = (t <= 1) ? 4.f : 1.f;
    const float sc1 = (t == 0) ? 4.f : 1.f;
    const float wq0 = (t == 0) ? 31.75f : 127.f;

    v4i acch[8], accl[8];
    const v4i zi = {0, 0, 0, 0};

    // ============ layer 0: h0 @ Whh0 (32 tiles, slot = j&3) ============
#pragma unroll
    for (int i = 0; i < 8; ++i) { acch[i] = zi; accl[i] = zi; }
    {
      v4i ah, al;
#pragma unroll 8
      for (int j = 0; j < 32; ++j) {
        const int i = j & 7, s = j & 3;
        if (i == 0) { int kc = j >> 3; ah = A0VH(kc); al = A0VL(kc); }
        wait_vmcnt<3>();
        v4i bb = __builtin_bit_cast(v4i, ring[w][s][lane]);
        acch[i] = __builtin_amdgcn_mfma_i32_16x16x64_i8(ah, bb, acch[i], 0, 0, 0);
        accl[i] = __builtin_amdgcn_mfma_i32_16x16x64_i8(al, bb, accl[i], 0, 0, 0);
        const int jn = j + 4;
        if (jn < 32) async_copy16(gp0 + (size_t)jn * 1024, &ring[w][s][0]);
        else         async_copy16(gp1 + (size_t)(jn - 32) * 1024, &ring[w][s][0]);
      }
    }
    __syncthreads();   // (a) L0 A-reads done; L1 prologue (tiles 0..3) landed

    // ---- cell 0: dequant + fp32 x-path from registers ----
    {
      float4 xa[4], xb[4];
#pragma unroll
      for (int r = 0; r < 4; ++r) {
        xa[r] = *(const float4*)&x_lds[(myrow + r) * 8];
        xb[r] = *(const float4*)&x_lds[(myrow + r) * 8 + 4];
      }
#pragma unroll
      for (int cc = 0; cc < 2; ++cc) {
        float gf4[4][4];
#pragma unroll
        for (int g = 0; g < 4; ++g) {
          int i = g * 2 + cc;
          float cs = csA0[i] * sc0;
#pragma unroll
          for (int r = 0; r < 4; ++r)
            gf4[g][r] = ((float)acch[i][r] + (float)accl[i][r] * (1.f / 254.f)) * cs + bA0[i];
        }
#pragma unroll
        for (int g = 0; g < 4; ++g) {
          int i = g * 2 + cc;
#pragma unroll
          for (int r = 0; r < 4; ++r)
            gf4[g][r] += xa[r].x * wx[i][0] + xa[r].y * wx[i][1]
                       + xa[r].z * wx[i][2] + xa[r].w * wx[i][3]
                       + xb[r].x * wx[i][4] + xb[r].y * wx[i][5]
                       + xb[r].z * wx[i][6] + xb[r].w * wx[i][7];
        }
#pragma unroll
        for (int r = 0; r < 4; ++r) {
          float iv = sigm(gf4[0][r]);
          float fv = sigm(gf4[1][r]);
          float gv = tanh_(gf4[2][r]);
          float ov = sigm(gf4[3][r]);
          c0r[cc][r] = fv * c0r[cc][r] + iv * gv;
          char hi, lo;
          q8pair(ov * tanh_(c0r[cc][r]), wq0, &hi, &lo);
          int off = ((16 + 2 * w + cc) * 16 + myrow + r) * 16 + l15;
          Xch[off] = hi; Xcl[off] = lo;
        }
      }
    }
    __syncthreads();   // (b) h0' visible

    // ============ layer 1: [h1|h0'] @ W1 (64 tiles, slot = j&3) ============
#pragma unroll
    for (int i = 0; i < 8; ++i) { acch[i] = zi; accl[i] = zi; }
    {
      v4i ah, al;
#pragma unroll 8
      for (int j = 0; j < 64; ++j) {
        const int i = j & 7, s = j & 3;
        if (i == 0) { int kc = j >> 3; ah = A1VH(kc); al = A1VL(kc); }
        wait_vmcnt<3>();
        v4i bb = __builtin_bit_cast(v4i, ring[w][s][lane]);
        acch[i] = __builtin_amdgcn_mfma_i32_16x16x64_i8(ah, bb, acch[i], 0, 0, 0);
        accl[i] = __builtin_amdgcn_mfma_i32_16x16x64_i8(al, bb, accl[i], 0, 0, 0);
        const int jn = j + 4;
        if (jn < 64) async_copy16(gp1 + (size_t)jn * 1024, &ring[w][s][0]);
        else         async_copy16(gp0 + (size_t)(jn - 64) * 1024, &ring[w][s][0]);
      }
    }
    __syncthreads();   // (c) L1 A-reads done; next step's L0 prologue landed

    // ---- cell 1: dequant + activations + h1 stores (i8 planes + bf16) ----
#pragma unroll
    for (int cc = 0; cc < 2; ++cc)
#pragma unroll
      for (int r = 0; r < 4; ++r) {
        float di = ((float)acch[0 + cc][r] + (float)accl[0 + cc][r] * (1.f / 254.f));
        float df = ((float)acch[2 + cc][r] + (float)accl[2 + cc][r] * (1.f / 254.f));
        float dg = ((float)acch[4 + cc][r] + (float)accl[4 + cc][r] * (1.f / 254.f));
        float dv = ((float)acch[6 + cc][r] + (float)accl[6 + cc][r] * (1.f / 254.f));
        float iv = sigm(di * csA1[0 + cc] * sc1 + bA1[0 + cc]);
        float fv = sigm(df * csA1[2 + cc] * sc1 + bA1[2 + cc]);
        float gv = tanh_(dg * csA1[4 + cc] * sc1 + bA1[4 + cc]);
        float ov = sigm(dv * csA1[6 + cc] * sc1 + bA1[6 + cc]);
        c1r[cc][r] = fv * c1r[cc][r] + iv * gv;
        float h = ov * tanh_(c1r[cc][r]);
        char hi, lo;
        q8pair(h, 127.f, &hi, &lo);
        int off = ((2 * w + cc) * 16 + myrow + r) * 16 + l15;
        Xch[off] = hi; Xcl[off] = lo;
        h1f[(myrow + r) * WSTR + jc0 + cc * 16] = f2bf(h);
      }
    __syncthreads();   // (d) h1 / h1f visible

    // ---- out projection from bf16 h1f + shfl reduce over opq ----
    {
      float s_ = 0.f;
#pragma unroll
      for (int i = 0; i < 16; ++i) {
        ushort4 hx = *(const ushort4*)&h1f[opr * WSTR + i * 16 + opq * 4];
        ushort4 wv = *(const ushort4*)&woutT[opd * WSTR + i * 16 + opq * 4];
        s_ += bf2f(hx.x) * bf2f(wv.x) + bf2f(hx.y) * bf2f(wv.y)
            + bf2f(hx.z) * bf2f(wv.z) + bf2f(hx.w) * bf2f(wv.w);
      }
      s_ += __shfl_xor(s_, 1);
      s_ += __shfl_xor(s_, 2);
      if (opq == 0)
        out[(size_t)(b0 + opr) * (TSTEPS * DDIM) + (size_t)t * DDIM + opd] =
            s_ + bo_out;
    }
    // next iteration's barrier (1) separates these reads/stores from rewrites
  }
#undef A0VH
#undef A0VL
#undef A1VH
#undef A1VL
}

extern "C" void kernel_launch(void* const* d_in, const int* in_sizes, int n_in,
                              void* d_out, int out_size, void* d_ws, size_t ws_size,
                              hipStream_t stream) {
  const float* z    = (const float*)d_in[0];
  const float* tgt  = (const float*)d_in[1];
  const float* Wfh  = (const float*)d_in[2];
  const float* bfh  = (const float*)d_in[3];
  const float* Wfc  = (const float*)d_in[4];
  const float* bfc  = (const float*)d_in[5];
  const float* Wih0 = (const float*)d_in[6];
  const float* Whh0 = (const float*)d_in[7];
  const float* bih0 = (const float*)d_in[8];
  const float* bhh0 = (const float*)d_in[9];
  const float* Wih1 = (const float*)d_in[10];
  const float* Whh1 = (const float*)d_in[11];
  const float* bih1 = (const float*)d_in[12];
  const float* bhh1 = (const float*)d_in[13];
  const float* Wout = (const float*)d_in[14];
  const float* bout = (const float*)d_in[15];

  // ws layout (bytes), total ~7.09 MB
  char* ws = (char*)d_ws;
  char*  p0   = ws;                                  // 262,144
  char*  p1   = ws + 262144;                         // 524,288
  char*  h0h  = ws + 786432;                         // 524,288
  char*  h0l  = ws + 1310720;                        // 524,288
  char*  h1h  = ws + 1835008;                        // 524,288
  char*  h1l  = ws + 2359296;                        // 524,288
  float* c0s  = (float*)(ws + 2883584);              // 2,097,152
  float* c1s  = (float*)(ws + 4980736);              // 2,097,152
  float* cs0  = (float*)(ws + 7077888);              // 4,096
  float* qs0  = (float*)(ws + 7081984);              // 4,096
  float* cs1  = (float*)(ws + 7086080);              // 4,096
  float* qs1  = (float*)(ws + 7090176);              // 4,096

  hipLaunchKernelGGL(init_state, dim3(BSZ * HDIM / 256), dim3(256), 0, stream,
                     z, Wfh, bfh, Wfc, bfc, h0h, h0l, h1h, h1l, c0s, c1s);
  hipLaunchKernelGGL(col_scales, dim3(8), dim3(256), 0, stream,
                     Whh0, Wih1, Whh1, cs0, qs0, cs1, qs1);
  hipLaunchKernelGGL(pack_i8, dim3(192), dim3(256), 0, stream,
                     Whh0, Wih1, Whh1, qs0, qs1, p0, p1);
  hipLaunchKernelGGL(lstm_run, dim3(NWG), dim3(NTH), 0, stream,
                     tgt, p0, p1, bih0, bhh0, bih1, bhh1, Wih0, Wout, bout,
                     h0h, h0l, h1h, h1l, c0s, c1s, cs0, cs1, (float*)d_out);
}